// Round 2
// baseline (287.510 us; speedup 1.0000x reference)
//
#include <hip/hip_runtime.h>
#include <hip/hip_bf16.h>
#include <math.h>

typedef __bf16 bf16x8 __attribute__((ext_vector_type(8)));
typedef float f32x4 __attribute__((ext_vector_type(4)));
typedef unsigned short u16x8 __attribute__((ext_vector_type(8)));
typedef unsigned short u16;

#define S_LEN 2048
#define DMODEL 1024
#define NH 16

__device__ __forceinline__ u16 f2bf(float f) {
    __bf16 b = (__bf16)f;
    return __builtin_bit_cast(u16, b);
}
__device__ __forceinline__ float bf2f(u16 u) {
    union { unsigned int i; float f; } v; v.i = ((unsigned int)u) << 16; return v.f;
}

// ---------- X f32 -> bf16 ----------
__global__ __launch_bounds__(256) void cvt_x(const float* __restrict__ in, u16* __restrict__ outp) {
    int i = (blockIdx.x * 256 + threadIdx.x) * 4;
    float4 v = *(const float4*)(in + i);
    outp[i + 0] = f2bf(v.x); outp[i + 1] = f2bf(v.y);
    outp[i + 2] = f2bf(v.z); outp[i + 3] = f2bf(v.w);
}

// ---------- W [1024][3072] f32 -> Wt [3072][1024] bf16 ----------
__global__ __launch_bounds__(256) void transpose_w(const float* __restrict__ W, u16* __restrict__ Wt) {
    __shared__ u16 tile[32][33];
    int n0 = blockIdx.x * 32, k0 = blockIdx.y * 32;
    int tx = threadIdx.x & 31, ty = threadIdx.x >> 5;
#pragma unroll
    for (int i = 0; i < 4; i++) {
        int k = ty + i * 8;
        tile[k][tx] = f2bf(W[(size_t)(k0 + k) * 3072 + n0 + tx]);
    }
    __syncthreads();
#pragma unroll
    for (int i = 0; i < 4; i++) {
        int n = ty + i * 8;
        Wt[(size_t)(n0 + n) * 1024 + k0 + tx] = tile[tx][n];
    }
}

// ---------- QKV GEMM (unchanged from R1) ----------
__global__ __launch_bounds__(256) void qkv_gemm(const u16* __restrict__ A, const u16* __restrict__ Bt,
                                                u16* __restrict__ C) {
    __shared__ alignas(16) u16 As[128 * 64];
    __shared__ alignas(16) u16 Bs[128 * 64];
    const int tid = threadIdx.x, l = tid & 63, w = tid >> 6;
    const int bm = blockIdx.y, bn = blockIdx.x;
    const int wm = w >> 1, wn = w & 1;
    const int c0 = l & 15, g = l >> 4;
    f32x4 acc[4][4] = {};
    for (int kt = 0; kt < 1024; kt += 64) {
        __syncthreads();
#pragma unroll
        for (int n = 0; n < 4; n++) {
            int i = tid + n * 256;
            int r = i >> 3, c = i & 7;
            u16x8 va = *(const u16x8*)(A + (size_t)(bm * 128 + r) * 1024 + kt + c * 8);
            *(u16x8*)((char*)As + r * 128 + ((c ^ (r & 7)) << 4)) = va;
            u16x8 vb = *(const u16x8*)(Bt + (size_t)(bn * 128 + r) * 1024 + kt + c * 8);
            *(u16x8*)((char*)Bs + r * 128 + ((c ^ (r & 7)) << 4)) = vb;
        }
        __syncthreads();
#pragma unroll
        for (int kk = 0; kk < 2; kk++) {
            bf16x8 af[4], bfr[4];
#pragma unroll
            for (int m = 0; m < 4; m++) {
                int row = wm * 64 + m * 16 + c0;
                af[m] = *(const bf16x8*)((const char*)As + row * 128 + (((g + kk * 4) ^ (row & 7)) << 4));
            }
#pragma unroll
            for (int n = 0; n < 4; n++) {
                int row = wn * 64 + n * 16 + c0;
                bfr[n] = *(const bf16x8*)((const char*)Bs + row * 128 + (((g + kk * 4) ^ (row & 7)) << 4));
            }
#pragma unroll
            for (int m = 0; m < 4; m++)
#pragma unroll
                for (int n = 0; n < 4; n++)
                    acc[m][n] = __builtin_amdgcn_mfma_f32_16x16x32_bf16(af[m], bfr[n], acc[m][n], 0, 0, 0);
        }
    }
#pragma unroll
    for (int m = 0; m < 4; m++)
#pragma unroll
        for (int n = 0; n < 4; n++)
#pragma unroll
            for (int j = 0; j < 4; j++) {
                int row = bm * 128 + wm * 64 + m * 16 + 4 * g + j;
                int col = bn * 128 + wn * 64 + n * 16 + c0;
                C[(size_t)row * 3072 + col] = f2bf(acc[m][n][j]);
            }
}

// ---------- V -> permuted V^T: Vtp[bh][d][spos], spos = (s&~63) | perm(s&63) ----------
// perm(t): kb=t>>4, g=(t>>2)&3, j=t&3 -> pos = 32*(kb>>1) + 8*g + 4*(kb&1) + j
// so that attn's PV B-frag (keys at pos 32*kk+8*g+jj) is one contiguous 16B load.
__global__ __launch_bounds__(256) void transpose_v(const u16* __restrict__ QKV, u16* __restrict__ Vtp) {
    __shared__ u16 tile[64][72];  // pitch 72 u16 = 144B, 16B-aligned vector writes
    const int bh = blockIdx.x >> 5, st = blockIdx.x & 31;
    const int b = bh >> 4, h = bh & 15;
    const u16* src = QKV + (size_t)b * S_LEN * 3072 + 2048 + h * 64;
    const int sl = threadIdx.x >> 2;            // 0..63
    const int cg = (threadIdx.x & 3) * 16;      // col group of 16
#pragma unroll
    for (int ii = 0; ii < 2; ii++) {
        u16x8 v = *(const u16x8*)(src + (size_t)(st * 64 + sl) * 3072 + cg + ii * 8);
        *(u16x8*)&tile[sl][cg + ii * 8] = v;
    }
    __syncthreads();
    const int dl = threadIdx.x >> 2;            // output row d 0..63
#pragma unroll
    for (int ii = 0; ii < 2; ii++) {
        u16x8 o;
#pragma unroll
        for (int q = 0; q < 8; q++) {
            int p = cg + ii * 8 + q;
            int kb = 2 * (p >> 5) + ((p >> 2) & 1);
            int t = kb * 16 + ((p >> 3) & 3) * 4 + (p & 3);
            o[q] = tile[t][dl];
        }
        *(u16x8*)(Vtp + ((size_t)bh * 64 + dl) * S_LEN + st * 64 + cg + ii * 8) = o;
    }
}

// ---------- Flash attention v2: zero LDS, zero barriers, swapped QK^T ----------
// Per wave: 16 q-rows (q = c0), KV tiles of 64. K/V read direct from global (L2-resident).
// Lane (g,c0): sc[kb][j] = P[key = kv+16kb+4g+j][q = c0].
// PV A-frag pf[kk] = {sc[2kk][0..3], sc[2kk+1][0..3]} (lane-local!); V read from permuted V^T.
__global__ __launch_bounds__(256, 4) void attn2(const u16* __restrict__ QKV, const u16* __restrict__ Vtp,
                                                float* __restrict__ out) {
    const int bid = blockIdx.x;
    const int wg = ((bid & 7) << 7) | (bid >> 3);   // XCD-chunked swizzle (1024 = 8*128, bijective)
    const int tid = threadIdx.x, l = tid & 63, w = tid >> 6;
    const int qt = wg & 31, bh = wg >> 5;
    const int b = bh >> 4, h = bh & 15;
    const int c0 = l & 15, g = l >> 4;
    const u16* Qb = QKV + (size_t)b * S_LEN * 3072 + h * 64;
    const u16* Kb = Qb + 1024;
    const u16* Vb = Vtp + (size_t)bh * 64 * S_LEN;
    const int qrow = qt * 64 + w * 16 + c0;

    // Q B-frags, scale (1/8)*log2(e) folded in; exp via exp2f
    bf16x8 qf[2];
    {
        const float qs = 0.125f * 1.44269504f;
#pragma unroll
        for (int kk = 0; kk < 2; kk++) {
            u16x8 v = *(const u16x8*)(Qb + (size_t)qrow * 3072 + kk * 32 + g * 8);
            bf16x8 q;
#pragma unroll
            for (int j = 0; j < 8; j++) q[j] = (__bf16)(bf2f(v[j]) * qs);
            qf[kk] = q;
        }
    }
    float m_r = -INFINITY, l_r = 0.f;
    f32x4 accO[4] = {};

    for (int kv = 0; kv < S_LEN; kv += 64) {
        // QK^T (swapped: A=K rows, B=Q^T): sc[kb] rows 4g+j = key, col c0 = q
        f32x4 sc[4] = {};
#pragma unroll
        for (int kb = 0; kb < 4; kb++) {
            const u16* kp = Kb + (size_t)(kv + kb * 16 + c0) * 3072 + g * 8;
            bf16x8 k0 = *(const bf16x8*)(kp);
            bf16x8 k1 = *(const bf16x8*)(kp + 32);
            sc[kb] = __builtin_amdgcn_mfma_f32_16x16x32_bf16(k0, qf[0], sc[kb], 0, 0, 0);
            sc[kb] = __builtin_amdgcn_mfma_f32_16x16x32_bf16(k1, qf[1], sc[kb], 0, 0, 0);
        }
        // issue V loads early (independent of softmax)
        bf16x8 vf[2][4];
#pragma unroll
        for (int kk = 0; kk < 2; kk++) {
            const u16* vp = Vb + kv + kk * 32 + g * 8;
#pragma unroll
            for (int n = 0; n < 4; n++)
                vf[kk][n] = *(const bf16x8*)(vp + (size_t)(n * 16 + c0) * S_LEN);
        }
        // online softmax: lane owns q=c0; stats reduced across the 4 g-groups
        float mx = fmaxf(fmaxf(fmaxf(sc[0][0], sc[0][1]), fmaxf(sc[0][2], sc[0][3])),
                         fmaxf(fmaxf(sc[1][0], sc[1][1]), fmaxf(sc[1][2], sc[1][3])));
        mx = fmaxf(mx, fmaxf(fmaxf(fmaxf(sc[2][0], sc[2][1]), fmaxf(sc[2][2], sc[2][3])),
                             fmaxf(fmaxf(sc[3][0], sc[3][1]), fmaxf(sc[3][2], sc[3][3]))));
        mx = fmaxf(mx, __shfl_xor(mx, 16));
        mx = fmaxf(mx, __shfl_xor(mx, 32));
        float mnew = fmaxf(m_r, mx);
        float alpha = exp2f(m_r - mnew);
        m_r = mnew;
        float ps = 0.f;
#pragma unroll
        for (int kb = 0; kb < 4; kb++)
#pragma unroll
            for (int j = 0; j < 4; j++) {
                float p = exp2f(sc[kb][j] - mnew);
                sc[kb][j] = p;
                ps += p;
            }
        ps += __shfl_xor(ps, 16);
        ps += __shfl_xor(ps, 32);
        l_r = l_r * alpha + ps;
        // rescale accO rows (row j is q=4g+j; fetch that q's alpha from lane 20g+j)
#pragma unroll
        for (int j = 0; j < 4; j++) {
            float aj = __shfl(alpha, 20 * g + j);
#pragma unroll
            for (int n = 0; n < 4; n++) accO[n][j] *= aj;
        }
        // PV: pf lane-local; V B-frag contiguous thanks to permuted storage
#pragma unroll
        for (int kk = 0; kk < 2; kk++) {
            bf16x8 pf;
#pragma unroll
            for (int j = 0; j < 4; j++) {
                pf[j]     = (__bf16)sc[2 * kk][j];
                pf[j + 4] = (__bf16)sc[2 * kk + 1][j];
            }
#pragma unroll
            for (int n = 0; n < 4; n++)
                accO[n] = __builtin_amdgcn_mfma_f32_16x16x32_bf16(pf, vf[kk][n], accO[n], 0, 0, 0);
        }
    }
    // epilogue: row j is q=4g+j -> fetch l from lane 20g+j
#pragma unroll
    for (int j = 0; j < 4; j++) {
        float inv = 1.0f / __shfl(l_r, 20 * g + j);
        int row = qt * 64 + w * 16 + 4 * g + j;
#pragma unroll
        for (int n = 0; n < 4; n++)
            out[((size_t)b * S_LEN + row) * DMODEL + h * 64 + n * 16 + c0] = accO[n][j] * inv;
    }
}

extern "C" void kernel_launch(void* const* d_in, const int* in_sizes, int n_in,
                              void* d_out, int out_size, void* d_ws, size_t ws_size,
                              hipStream_t stream) {
    const float* X = (const float*)d_in[0];
    const float* W = (const float*)d_in[1];
    float* out = (float*)d_out;

    u16* Xb  = (u16*)d_ws;                        // 4096*1024 bf16
    u16* Wt  = Xb + (size_t)4096 * 1024;          // 3072*1024 bf16
    u16* QKV = Wt + (size_t)3072 * 1024;          // 4096*3072 bf16
    u16* Vtp = QKV + (size_t)4096 * 3072;         // 32*64*2048 bf16 (~8.4MB; ws total ~48MB)

    cvt_x<<<4096, 256, 0, stream>>>(X, Xb);
    transpose_w<<<dim3(96, 32), 256, 0, stream>>>(W, Wt);
    qkv_gemm<<<dim3(24, 32), 256, 0, stream>>>(Xb, Wt, QKV);
    transpose_v<<<1024, 256, 0, stream>>>(QKV, Vtp);
    attn2<<<1024, 256, 0, stream>>>(QKV, Vtp, out);
}

// Round 3
// 131.264 us; speedup vs baseline: 2.1903x; 2.1903x over previous
//
#include <hip/hip_runtime.h>
#include <hip/hip_bf16.h>
#include <math.h>

typedef __bf16 bf16x8 __attribute__((ext_vector_type(8)));
typedef float f32x4 __attribute__((ext_vector_type(4)));
typedef unsigned short u16x8 __attribute__((ext_vector_type(8)));
typedef unsigned short u16;

#define S_LEN 2048
#define DMODEL 1024
#define NH 16

__device__ __forceinline__ u16 f2bf(float f) {
    __bf16 b = (__bf16)f;
    return __builtin_bit_cast(u16, b);
}
__device__ __forceinline__ float bf2f(u16 u) {
    union { unsigned int i; float f; } v; v.i = ((unsigned int)u) << 16; return v.f;
}

// global -> LDS direct copy, 16B per lane. lds dest must be the WAVE-UNIFORM base
// (hardware adds lane*16); global src is per-lane (pre-swizzled for XOR layouts).
__device__ __forceinline__ void gload16(const u16* g, u16* lds_base) {
    __builtin_amdgcn_global_load_lds(
        (const __attribute__((address_space(1))) unsigned int*)g,
        (__attribute__((address_space(3))) unsigned int*)lds_base,
        16, 0, 0);
}

// ---------- X f32 -> bf16 ----------
__global__ __launch_bounds__(256) void cvt_x(const float* __restrict__ in, u16* __restrict__ outp) {
    int i = (blockIdx.x * 256 + threadIdx.x) * 4;
    float4 v = *(const float4*)(in + i);
    outp[i + 0] = f2bf(v.x); outp[i + 1] = f2bf(v.y);
    outp[i + 2] = f2bf(v.z); outp[i + 3] = f2bf(v.w);
}

// ---------- W [1024][3072] f32 -> Wt [3072][1024] bf16 ----------
__global__ __launch_bounds__(256) void transpose_w(const float* __restrict__ W, u16* __restrict__ Wt) {
    __shared__ u16 tile[32][33];
    int n0 = blockIdx.x * 32, k0 = blockIdx.y * 32;
    int tx = threadIdx.x & 31, ty = threadIdx.x >> 5;
#pragma unroll
    for (int i = 0; i < 4; i++) {
        int k = ty + i * 8;
        tile[k][tx] = f2bf(W[(size_t)(k0 + k) * 3072 + n0 + tx]);
    }
    __syncthreads();
#pragma unroll
    for (int i = 0; i < 4; i++) {
        int n = ty + i * 8;
        Wt[(size_t)(n0 + n) * 1024 + k0 + tx] = tile[tx][n];
    }
}

// ---------- QKV GEMM: global_load_lds staging (m97 pattern), pre-swizzled source ----------
// LDS linear chunk (r,c) holds global chunk (r, c^(r&7)); read chunk q at q^(r&7). Same
// mapping as R1's reg-staged swizzle; read side unchanged.
__global__ __launch_bounds__(256) void qkv_gemm(const u16* __restrict__ A, const u16* __restrict__ Bt,
                                                u16* __restrict__ C) {
    __shared__ alignas(16) u16 As[128 * 64];
    __shared__ alignas(16) u16 Bs[128 * 64];
    const int tid = threadIdx.x, l = tid & 63, w = tid >> 6;
    const int bm = blockIdx.y, bn = blockIdx.x;
    const int wm = w >> 1, wn = w & 1;
    const int c0 = l & 15, g = l >> 4;
    f32x4 acc[4][4] = {};
    for (int kt = 0; kt < 1024; kt += 64) {
        __syncthreads();
#pragma unroll
        for (int n = 0; n < 4; n++) {
            int i = tid + n * 256;
            int r = i >> 3, c = i & 7;
            int cs = c ^ (r & 7);
            u16* dstA = As + (size_t)(w * 64 + n * 256) * 8;   // wave-uniform
            u16* dstB = Bs + (size_t)(w * 64 + n * 256) * 8;
            gload16(A + (size_t)(bm * 128 + r) * 1024 + kt + cs * 8, dstA);
            gload16(Bt + (size_t)(bn * 128 + r) * 1024 + kt + cs * 8, dstB);
        }
        __syncthreads();
#pragma unroll
        for (int kk = 0; kk < 2; kk++) {
            bf16x8 af[4], bfr[4];
#pragma unroll
            for (int m = 0; m < 4; m++) {
                int row = wm * 64 + m * 16 + c0;
                af[m] = *(const bf16x8*)((const char*)As + row * 128 + (((g + kk * 4) ^ (row & 7)) << 4));
            }
#pragma unroll
            for (int n = 0; n < 4; n++) {
                int row = wn * 64 + n * 16 + c0;
                bfr[n] = *(const bf16x8*)((const char*)Bs + row * 128 + (((g + kk * 4) ^ (row & 7)) << 4));
            }
#pragma unroll
            for (int m = 0; m < 4; m++)
#pragma unroll
                for (int n = 0; n < 4; n++)
                    acc[m][n] = __builtin_amdgcn_mfma_f32_16x16x32_bf16(af[m], bfr[n], acc[m][n], 0, 0, 0);
        }
    }
#pragma unroll
    for (int m = 0; m < 4; m++)
#pragma unroll
        for (int n = 0; n < 4; n++)
#pragma unroll
            for (int j = 0; j < 4; j++) {
                int row = bm * 128 + wm * 64 + m * 16 + 4 * g + j;
                int col = bn * 128 + wn * 64 + n * 16 + c0;
                C[(size_t)row * 3072 + col] = f2bf(acc[m][n][j]);
            }
}

// ---------- V -> permuted V^T: Vtp[bh][d][spos], spos = (s&~63) | perm(s&63) ----------
__global__ __launch_bounds__(256) void transpose_v(const u16* __restrict__ QKV, u16* __restrict__ Vtp) {
    __shared__ u16 tile[64][72];
    const int bh = blockIdx.x >> 5, st = blockIdx.x & 31;
    const int b = bh >> 4, h = bh & 15;
    const u16* src = QKV + (size_t)b * S_LEN * 3072 + 2048 + h * 64;
    const int sl = threadIdx.x >> 2;
    const int cg = (threadIdx.x & 3) * 16;
#pragma unroll
    for (int ii = 0; ii < 2; ii++) {
        u16x8 v = *(const u16x8*)(src + (size_t)(st * 64 + sl) * 3072 + cg + ii * 8);
        *(u16x8*)&tile[sl][cg + ii * 8] = v;
    }
    __syncthreads();
    const int dl = threadIdx.x >> 2;
#pragma unroll
    for (int ii = 0; ii < 2; ii++) {
        u16x8 o;
#pragma unroll
        for (int q = 0; q < 8; q++) {
            int p = cg + ii * 8 + q;
            int kb = 2 * (p >> 5) + ((p >> 2) & 1);
            int t = kb * 16 + ((p >> 3) & 3) * 4 + (p & 3);
            o[q] = tile[t][dl];
        }
        *(u16x8*)(Vtp + ((size_t)bh * 64 + dl) * S_LEN + st * 64 + cg + ii * 8) = o;
    }
}

// ---------- Flash attention v3: LDS-staged K/V (double-buffered, 1 barrier/tile),
// swapped QK^T, lane-local softmax + P->PV (no shuffles, no P round-trip) ----------
__global__ __launch_bounds__(256, 4) void attn3(const u16* __restrict__ QKV, const u16* __restrict__ Vtp,
                                                float* __restrict__ out) {
    __shared__ alignas(16) u16 Ks[2][64 * 64];   // [key][d] chunks, chunk^=(key&7)
    __shared__ alignas(16) u16 Vs[2][64 * 64];   // [d][keypos] chunks, chunk^=(d&7)
    const int bid = blockIdx.x;
    const int wg = ((bid & 7) << 7) | (bid >> 3);   // XCD-chunked swizzle (bijective: 1024=8*128)
    const int tid = threadIdx.x, l = tid & 63, w = tid >> 6;
    const int qt = wg & 31, bh = wg >> 5;
    const int b = bh >> 4, h = bh & 15;
    const int c0 = l & 15, g = l >> 4;
    const u16* Qb = QKV + (size_t)b * S_LEN * 3072 + h * 64;
    const u16* Kb = Qb + 1024;
    const u16* Vb = Vtp + (size_t)bh * 64 * S_LEN;
    const int qrow = qt * 64 + w * 16 + c0;

    // staging geometry: 512 chunks of 16B per operand tile, 2 per thread
    const int i0 = tid, i1 = tid + 256;
    const int r0 = i0 >> 3, cs0 = (i0 & 7) ^ (r0 & 7);
    const int r1 = i1 >> 3, cs1 = (i1 & 7) ^ (r1 & 7);

    // Q B-frags, scale (1/8)*log2(e) folded in; exp via exp2f
    bf16x8 qf[2];
    {
        const float qs = 0.125f * 1.44269504f;
#pragma unroll
        for (int kk = 0; kk < 2; kk++) {
            u16x8 v = *(const u16x8*)(Qb + (size_t)qrow * 3072 + kk * 32 + g * 8);
            bf16x8 q;
#pragma unroll
            for (int j = 0; j < 8; j++) q[j] = (__bf16)(bf2f(v[j]) * qs);
            qf[kk] = q;
        }
    }
    float m_r = -INFINITY, l_r = 0.f;
    f32x4 accO[4] = {};

    // prologue: stage tile 0 into buf 0
    {
        gload16(Kb + (size_t)r0 * 3072 + cs0 * 8, Ks[0] + (size_t)(w * 64) * 8);
        gload16(Kb + (size_t)r1 * 3072 + cs1 * 8, Ks[0] + (size_t)(w * 64 + 256) * 8);
        gload16(Vb + (size_t)r0 * S_LEN + cs0 * 8, Vs[0] + (size_t)(w * 64) * 8);
        gload16(Vb + (size_t)r1 * S_LEN + cs1 * 8, Vs[0] + (size_t)(w * 64 + 256) * 8);
    }

    for (int t = 0; t < 32; t++) {
        const int cur = t & 1;
        __syncthreads();  // buf[cur] staged (vmcnt drained) + prev-iter reads of buf[cur^1] done
        if (t + 1 < 32) {
            const int kvn = (t + 1) * 64;
            gload16(Kb + (size_t)(kvn + r0) * 3072 + cs0 * 8, Ks[cur ^ 1] + (size_t)(w * 64) * 8);
            gload16(Kb + (size_t)(kvn + r1) * 3072 + cs1 * 8, Ks[cur ^ 1] + (size_t)(w * 64 + 256) * 8);
            gload16(Vb + (size_t)r0 * S_LEN + kvn + cs0 * 8, Vs[cur ^ 1] + (size_t)(w * 64) * 8);
            gload16(Vb + (size_t)r1 * S_LEN + kvn + cs1 * 8, Vs[cur ^ 1] + (size_t)(w * 64 + 256) * 8);
        }
        // QK^T (swapped): sc[kb] rows 4g+j = key, col c0 = q
        f32x4 sc[4] = {};
#pragma unroll
        for (int kb = 0; kb < 4; kb++) {
            int key = kb * 16 + c0;
#pragma unroll
            for (int kk = 0; kk < 2; kk++) {
                bf16x8 kf = *(const bf16x8*)((const char*)Ks[cur] + key * 128 + (((g + kk * 4) ^ (key & 7)) << 4));
                sc[kb] = __builtin_amdgcn_mfma_f32_16x16x32_bf16(kf, qf[kk], sc[kb], 0, 0, 0);
            }
        }
        // online softmax: lane owns q=c0
        float mx = fmaxf(fmaxf(fmaxf(sc[0][0], sc[0][1]), fmaxf(sc[0][2], sc[0][3])),
                         fmaxf(fmaxf(sc[1][0], sc[1][1]), fmaxf(sc[1][2], sc[1][3])));
        mx = fmaxf(mx, fmaxf(fmaxf(fmaxf(sc[2][0], sc[2][1]), fmaxf(sc[2][2], sc[2][3])),
                             fmaxf(fmaxf(sc[3][0], sc[3][1]), fmaxf(sc[3][2], sc[3][3]))));
        mx = fmaxf(mx, __shfl_xor(mx, 16));
        mx = fmaxf(mx, __shfl_xor(mx, 32));
        float mnew = fmaxf(m_r, mx);
        float alpha = exp2f(m_r - mnew);
        m_r = mnew;
        float ps = 0.f;
#pragma unroll
        for (int kb = 0; kb < 4; kb++)
#pragma unroll
            for (int j = 0; j < 4; j++) {
                float p = exp2f(sc[kb][j] - mnew);
                sc[kb][j] = p;
                ps += p;
            }
        ps += __shfl_xor(ps, 16);
        ps += __shfl_xor(ps, 32);
        l_r = l_r * alpha + ps;
#pragma unroll
        for (int j = 0; j < 4; j++) {
            float aj = __shfl(alpha, 20 * g + j);
#pragma unroll
            for (int n = 0; n < 4; n++) accO[n][j] *= aj;
        }
        // PV: pf lane-local; V B-frags from LDS (2-way aliased reads = free)
#pragma unroll
        for (int kk = 0; kk < 2; kk++) {
            bf16x8 pf;
#pragma unroll
            for (int j = 0; j < 4; j++) {
                pf[j]     = (__bf16)sc[2 * kk][j];
                pf[j + 4] = (__bf16)sc[2 * kk + 1][j];
            }
#pragma unroll
            for (int n = 0; n < 4; n++) {
                int d = n * 16 + c0;
                bf16x8 vf = *(const bf16x8*)((const char*)Vs[cur] + d * 128 + (((g + 4 * kk) ^ (d & 7)) << 4));
                accO[n] = __builtin_amdgcn_mfma_f32_16x16x32_bf16(pf, vf, accO[n], 0, 0, 0);
            }
        }
    }
    // epilogue: row j is q=4g+j -> fetch l from lane 20g+j
#pragma unroll
    for (int j = 0; j < 4; j++) {
        float inv = 1.0f / __shfl(l_r, 20 * g + j);
        int row = qt * 64 + w * 16 + 4 * g + j;
#pragma unroll
        for (int n = 0; n < 4; n++)
            out[((size_t)b * S_LEN + row) * DMODEL + h * 64 + n * 16 + c0] = accO[n][j] * inv;
    }
}

extern "C" void kernel_launch(void* const* d_in, const int* in_sizes, int n_in,
                              void* d_out, int out_size, void* d_ws, size_t ws_size,
                              hipStream_t stream) {
    const float* X = (const float*)d_in[0];
    const float* W = (const float*)d_in[1];
    float* out = (float*)d_out;

    u16* Xb  = (u16*)d_ws;                        // 4096*1024 bf16
    u16* Wt  = Xb + (size_t)4096 * 1024;          // 3072*1024 bf16
    u16* QKV = Wt + (size_t)3072 * 1024;          // 4096*3072 bf16
    u16* Vtp = QKV + (size_t)4096 * 3072;         // 32*64*2048 bf16 (~48MB total)

    cvt_x<<<4096, 256, 0, stream>>>(X, Xb);
    transpose_w<<<dim3(96, 32), 256, 0, stream>>>(W, Wt);
    qkv_gemm<<<dim3(24, 32), 256, 0, stream>>>(Xb, Wt, QKV);
    transpose_v<<<1024, 256, 0, stream>>>(QKV, Vtp);
    attn3<<<1024, 256, 0, stream>>>(QKV, Vtp, out);
}

// Round 4
// 113.740 us; speedup vs baseline: 2.5278x; 1.1541x over previous
//
#include <hip/hip_runtime.h>
#include <hip/hip_bf16.h>
#include <math.h>

typedef __bf16 bf16x8 __attribute__((ext_vector_type(8)));
typedef float f32x4 __attribute__((ext_vector_type(4)));
typedef unsigned short u16x8 __attribute__((ext_vector_type(8)));
typedef unsigned short u16;

#define S_LEN 2048
#define DMODEL 1024
#define NH 16

__device__ __forceinline__ u16 f2bf(float f) {
    __bf16 b = (__bf16)f;
    return __builtin_bit_cast(u16, b);
}
__device__ __forceinline__ float bf2f(u16 u) {
    union { unsigned int i; float f; } v; v.i = ((unsigned int)u) << 16; return v.f;
}

// global -> LDS direct copy, 16B per lane. lds dest must be the WAVE-UNIFORM base
// (hardware adds lane*16); global src is per-lane (pre-swizzled for XOR layouts).
__device__ __forceinline__ void gload16(const u16* g, u16* lds_base) {
    __builtin_amdgcn_global_load_lds(
        (const __attribute__((address_space(1))) unsigned int*)g,
        (__attribute__((address_space(3))) unsigned int*)lds_base,
        16, 0, 0);
}

// ---------- X f32 -> bf16 ----------
__global__ __launch_bounds__(256) void cvt_x(const float* __restrict__ in, u16* __restrict__ outp) {
    int i = (blockIdx.x * 256 + threadIdx.x) * 4;
    float4 v = *(const float4*)(in + i);
    outp[i + 0] = f2bf(v.x); outp[i + 1] = f2bf(v.y);
    outp[i + 2] = f2bf(v.z); outp[i + 3] = f2bf(v.w);
}

// ---------- W [1024][3072] f32 -> Wt [3072][1024] bf16 ----------
__global__ __launch_bounds__(256) void transpose_w(const float* __restrict__ W, u16* __restrict__ Wt) {
    __shared__ u16 tile[32][33];
    int n0 = blockIdx.x * 32, k0 = blockIdx.y * 32;
    int tx = threadIdx.x & 31, ty = threadIdx.x >> 5;
#pragma unroll
    for (int i = 0; i < 4; i++) {
        int k = ty + i * 8;
        tile[k][tx] = f2bf(W[(size_t)(k0 + k) * 3072 + n0 + tx]);
    }
    __syncthreads();
#pragma unroll
    for (int i = 0; i < 4; i++) {
        int n = ty + i * 8;
        Wt[(size_t)(n0 + n) * 1024 + k0 + tx] = tile[tx][n];
    }
}

// ---------- QKV GEMM: global_load_lds staging (m97 pattern), pre-swizzled source ----------
__global__ __launch_bounds__(256) void qkv_gemm(const u16* __restrict__ A, const u16* __restrict__ Bt,
                                                u16* __restrict__ C) {
    __shared__ alignas(16) u16 As[128 * 64];
    __shared__ alignas(16) u16 Bs[128 * 64];
    const int tid = threadIdx.x, l = tid & 63, w = tid >> 6;
    const int bm = blockIdx.y, bn = blockIdx.x;
    const int wm = w >> 1, wn = w & 1;
    const int c0 = l & 15, g = l >> 4;
    f32x4 acc[4][4] = {};
    for (int kt = 0; kt < 1024; kt += 64) {
        __syncthreads();
#pragma unroll
        for (int n = 0; n < 4; n++) {
            int i = tid + n * 256;
            int r = i >> 3, c = i & 7;
            int cs = c ^ (r & 7);
            u16* dstA = As + (size_t)(w * 64 + n * 256) * 8;   // wave-uniform
            u16* dstB = Bs + (size_t)(w * 64 + n * 256) * 8;
            gload16(A + (size_t)(bm * 128 + r) * 1024 + kt + cs * 8, dstA);
            gload16(Bt + (size_t)(bn * 128 + r) * 1024 + kt + cs * 8, dstB);
        }
        __syncthreads();
#pragma unroll
        for (int kk = 0; kk < 2; kk++) {
            bf16x8 af[4], bfr[4];
#pragma unroll
            for (int m = 0; m < 4; m++) {
                int row = wm * 64 + m * 16 + c0;
                af[m] = *(const bf16x8*)((const char*)As + row * 128 + (((g + kk * 4) ^ (row & 7)) << 4));
            }
#pragma unroll
            for (int n = 0; n < 4; n++) {
                int row = wn * 64 + n * 16 + c0;
                bfr[n] = *(const bf16x8*)((const char*)Bs + row * 128 + (((g + kk * 4) ^ (row & 7)) << 4));
            }
#pragma unroll
            for (int m = 0; m < 4; m++)
#pragma unroll
                for (int n = 0; n < 4; n++)
                    acc[m][n] = __builtin_amdgcn_mfma_f32_16x16x32_bf16(af[m], bfr[n], acc[m][n], 0, 0, 0);
        }
    }
#pragma unroll
    for (int m = 0; m < 4; m++)
#pragma unroll
        for (int n = 0; n < 4; n++)
#pragma unroll
            for (int j = 0; j < 4; j++) {
                int row = bm * 128 + wm * 64 + m * 16 + 4 * g + j;
                int col = bn * 128 + wn * 64 + n * 16 + c0;
                C[(size_t)row * 3072 + col] = f2bf(acc[m][n][j]);
            }
}

// ---------- V -> permuted V^T: Vtp[bh][d][spos], spos = (s&~63) | perm(s&63) ----------
__global__ __launch_bounds__(256) void transpose_v(const u16* __restrict__ QKV, u16* __restrict__ Vtp) {
    __shared__ u16 tile[64][72];
    const int bh = blockIdx.x >> 5, st = blockIdx.x & 31;
    const int b = bh >> 4, h = bh & 15;
    const u16* src = QKV + (size_t)b * S_LEN * 3072 + 2048 + h * 64;
    const int sl = threadIdx.x >> 2;
    const int cg = (threadIdx.x & 3) * 16;
#pragma unroll
    for (int ii = 0; ii < 2; ii++) {
        u16x8 v = *(const u16x8*)(src + (size_t)(st * 64 + sl) * 3072 + cg + ii * 8);
        *(u16x8*)&tile[sl][cg + ii * 8] = v;
    }
    __syncthreads();
    const int dl = threadIdx.x >> 2;
#pragma unroll
    for (int ii = 0; ii < 2; ii++) {
        u16x8 o;
#pragma unroll
        for (int q = 0; q < 8; q++) {
            int p = cg + ii * 8 + q;
            int kb = 2 * (p >> 5) + ((p >> 2) & 1);
            int t = kb * 16 + ((p >> 3) & 3) * 4 + (p & 3);
            o[q] = tile[t][dl];
        }
        *(u16x8*)(Vtp + ((size_t)bh * 64 + dl) * S_LEN + st * 64 + cg + ii * 8) = o;
    }
}

// ---------- Flash attention v4: R3 structure + raw exp2 + defer-max(T13) + max3 tree
// + hoisted V ds_reads + s_setprio around MFMA (T5) ----------
__global__ __launch_bounds__(256, 4) void attn4(const u16* __restrict__ QKV, const u16* __restrict__ Vtp,
                                                float* __restrict__ out) {
    __shared__ alignas(16) u16 Ks[2][64 * 64];   // [key][d] chunks, chunk^=(key&7)
    __shared__ alignas(16) u16 Vs[2][64 * 64];   // [d][keypos] chunks, chunk^=(d&7)
    const int bid = blockIdx.x;
    const int wg = ((bid & 7) << 7) | (bid >> 3);   // XCD-chunked swizzle (bijective: 1024=8*128)
    const int tid = threadIdx.x, l = tid & 63, w = tid >> 6;
    const int qt = wg & 31, bh = wg >> 5;
    const int b = bh >> 4, h = bh & 15;
    const int c0 = l & 15, g = l >> 4;
    const u16* Qb = QKV + (size_t)b * S_LEN * 3072 + h * 64;
    const u16* Kb = Qb + 1024;
    const u16* Vb = Vtp + (size_t)bh * 64 * S_LEN;
    const int qrow = qt * 64 + w * 16 + c0;

    const int i0 = tid, i1 = tid + 256;
    const int r0 = i0 >> 3, cs0 = (i0 & 7) ^ (r0 & 7);
    const int r1 = i1 >> 3, cs1 = (i1 & 7) ^ (r1 & 7);

    bf16x8 qf[2];
    {
        const float qs = 0.125f * 1.44269504f;   // fold 1/sqrt(64) * log2(e); exp via v_exp_f32
#pragma unroll
        for (int kk = 0; kk < 2; kk++) {
            u16x8 v = *(const u16x8*)(Qb + (size_t)qrow * 3072 + kk * 32 + g * 8);
            bf16x8 q;
#pragma unroll
            for (int j = 0; j < 8; j++) q[j] = (__bf16)(bf2f(v[j]) * qs);
            qf[kk] = q;
        }
    }
    float m_r = -INFINITY, l_r = 0.f;
    f32x4 accO[4] = {};

    // prologue: stage tile 0 into buf 0
    gload16(Kb + (size_t)r0 * 3072 + cs0 * 8, Ks[0] + (size_t)(w * 64) * 8);
    gload16(Kb + (size_t)r1 * 3072 + cs1 * 8, Ks[0] + (size_t)(w * 64 + 256) * 8);
    gload16(Vb + (size_t)r0 * S_LEN + cs0 * 8, Vs[0] + (size_t)(w * 64) * 8);
    gload16(Vb + (size_t)r1 * S_LEN + cs1 * 8, Vs[0] + (size_t)(w * 64 + 256) * 8);

    for (int t = 0; t < 32; t++) {
        const int cur = t & 1;
        __syncthreads();  // buf[cur] staged (vmcnt drained at this barrier) + prev reads done
        if (t + 1 < 32) {
            const int kvn = (t + 1) * 64;
            gload16(Kb + (size_t)(kvn + r0) * 3072 + cs0 * 8, Ks[cur ^ 1] + (size_t)(w * 64) * 8);
            gload16(Kb + (size_t)(kvn + r1) * 3072 + cs1 * 8, Ks[cur ^ 1] + (size_t)(w * 64 + 256) * 8);
            gload16(Vb + (size_t)r0 * S_LEN + kvn + cs0 * 8, Vs[cur ^ 1] + (size_t)(w * 64) * 8);
            gload16(Vb + (size_t)r1 * S_LEN + kvn + cs1 * 8, Vs[cur ^ 1] + (size_t)(w * 64 + 256) * 8);
        }
        // hoist V fragment reads: latency hides under QK^T + softmax
        bf16x8 vf[2][4];
#pragma unroll
        for (int kk = 0; kk < 2; kk++)
#pragma unroll
            for (int n = 0; n < 4; n++) {
                int d = n * 16 + c0;
                vf[kk][n] = *(const bf16x8*)((const char*)Vs[cur] + d * 128 + (((g + 4 * kk) ^ (d & 7)) << 4));
            }
        // QK^T (swapped): sc[kb] rows 4g+j = key, col c0 = q
        f32x4 sc[4] = {};
        __builtin_amdgcn_s_setprio(1);
#pragma unroll
        for (int kb = 0; kb < 4; kb++) {
            int key = kb * 16 + c0;
#pragma unroll
            for (int kk = 0; kk < 2; kk++) {
                bf16x8 kf = *(const bf16x8*)((const char*)Ks[cur] + key * 128 + (((g + kk * 4) ^ (key & 7)) << 4));
                sc[kb] = __builtin_amdgcn_mfma_f32_16x16x32_bf16(kf, qf[kk], sc[kb], 0, 0, 0);
            }
        }
        __builtin_amdgcn_s_setprio(0);
        // tile max (max3-friendly triplets), reduce across the 4 g-groups
        float m0 = fmaxf(fmaxf(sc[0][0], sc[0][1]), sc[0][2]);
        float m1 = fmaxf(fmaxf(sc[0][3], sc[1][0]), sc[1][1]);
        float m2 = fmaxf(fmaxf(sc[1][2], sc[1][3]), sc[2][0]);
        float m3 = fmaxf(fmaxf(sc[2][1], sc[2][2]), sc[2][3]);
        float m4 = fmaxf(fmaxf(sc[3][0], sc[3][1]), sc[3][2]);
        float mx = fmaxf(fmaxf(fmaxf(m0, m1), m2), fmaxf(fmaxf(m3, m4), sc[3][3]));
        mx = fmaxf(mx, __shfl_xor(mx, 16));
        mx = fmaxf(mx, __shfl_xor(mx, 32));
        // defer-max (T13): only rescale when the running max grew by > 8 (log2 domain)
        if (!__all(mx <= m_r + 8.f)) {
            float mnew = fmaxf(m_r, mx);
            float alpha = __builtin_amdgcn_exp2f(m_r - mnew);
            l_r *= alpha;
            m_r = mnew;
#pragma unroll
            for (int j = 0; j < 4; j++) {
                float aj = __shfl(alpha, 20 * g + j);
#pragma unroll
                for (int n = 0; n < 4; n++) accO[n][j] *= aj;
            }
        }
        float ps = 0.f;
#pragma unroll
        for (int kb = 0; kb < 4; kb++)
#pragma unroll
            for (int j = 0; j < 4; j++) {
                float p = __builtin_amdgcn_exp2f(sc[kb][j] - m_r);
                sc[kb][j] = p;
                ps += p;
            }
        ps += __shfl_xor(ps, 16);
        ps += __shfl_xor(ps, 32);
        l_r += ps;
        // PV: pf lane-local; vf preloaded
        __builtin_amdgcn_s_setprio(1);
#pragma unroll
        for (int kk = 0; kk < 2; kk++) {
            bf16x8 pf;
#pragma unroll
            for (int j = 0; j < 4; j++) {
                pf[j]     = (__bf16)sc[2 * kk][j];
                pf[j + 4] = (__bf16)sc[2 * kk + 1][j];
            }
#pragma unroll
            for (int n = 0; n < 4; n++)
                accO[n] = __builtin_amdgcn_mfma_f32_16x16x32_bf16(pf, vf[kk][n], accO[n], 0, 0, 0);
        }
        __builtin_amdgcn_s_setprio(0);
    }
    // epilogue: row j is q=4g+j -> fetch l from lane 20g+j
#pragma unroll
    for (int j = 0; j < 4; j++) {
        float inv = 1.0f / __shfl(l_r, 20 * g + j);
        int row = qt * 64 + w * 16 + 4 * g + j;
#pragma unroll
        for (int n = 0; n < 4; n++)
            out[((size_t)b * S_LEN + row) * DMODEL + h * 64 + n * 16 + c0] = accO[n][j] * inv;
    }
}

extern "C" void kernel_launch(void* const* d_in, const int* in_sizes, int n_in,
                              void* d_out, int out_size, void* d_ws, size_t ws_size,
                              hipStream_t stream) {
    const float* X = (const float*)d_in[0];
    const float* W = (const float*)d_in[1];
    float* out = (float*)d_out;

    u16* Xb  = (u16*)d_ws;                        // 4096*1024 bf16
    u16* Wt  = Xb + (size_t)4096 * 1024;          // 3072*1024 bf16
    u16* QKV = Wt + (size_t)3072 * 1024;          // 4096*3072 bf16
    u16* Vtp = QKV + (size_t)4096 * 3072;         // 32*64*2048 bf16 (~48MB total)

    cvt_x<<<4096, 256, 0, stream>>>(X, Xb);
    transpose_w<<<dim3(96, 32), 256, 0, stream>>>(W, Wt);
    qkv_gemm<<<dim3(24, 32), 256, 0, stream>>>(Xb, Wt, QKV);
    transpose_v<<<1024, 256, 0, stream>>>(QKV, Vtp);
    attn4<<<1024, 256, 0, stream>>>(QKV, Vtp, out);
}

// Round 5
// 112.689 us; speedup vs baseline: 2.5514x; 1.0093x over previous
//
#include <hip/hip_runtime.h>
#include <hip/hip_bf16.h>
#include <math.h>

typedef __bf16 bf16x8 __attribute__((ext_vector_type(8)));
typedef float f32x4 __attribute__((ext_vector_type(4)));
typedef unsigned short u16x8 __attribute__((ext_vector_type(8)));
typedef unsigned short u16;

#define S_LEN 2048
#define DMODEL 1024
#define NH 16

__device__ __forceinline__ u16 f2bf(float f) {
    __bf16 b = (__bf16)f;
    return __builtin_bit_cast(u16, b);
}
__device__ __forceinline__ float bf2f(u16 u) {
    union { unsigned int i; float f; } v; v.i = ((unsigned int)u) << 16; return v.f;
}

// global -> LDS direct copy, 16B per lane. lds dest is the WAVE-UNIFORM base
// (hardware adds lane*16); global src is per-lane (pre-swizzled for XOR layouts).
__device__ __forceinline__ void gload16(const u16* g, u16* lds_base) {
    __builtin_amdgcn_global_load_lds(
        (const __attribute__((address_space(1))) unsigned int*)g,
        (__attribute__((address_space(3))) unsigned int*)lds_base,
        16, 0, 0);
}

// ---------- X f32 -> bf16 ----------
__global__ __launch_bounds__(256) void cvt_x(const float* __restrict__ in, u16* __restrict__ outp) {
    int i = (blockIdx.x * 256 + threadIdx.x) * 4;
    float4 v = *(const float4*)(in + i);
    outp[i + 0] = f2bf(v.x); outp[i + 1] = f2bf(v.y);
    outp[i + 2] = f2bf(v.z); outp[i + 3] = f2bf(v.w);
}

// ---------- W [1024][3072] f32 -> Wt [3072][1024] bf16 ----------
__global__ __launch_bounds__(256) void transpose_w(const float* __restrict__ W, u16* __restrict__ Wt) {
    __shared__ u16 tile[32][33];
    int n0 = blockIdx.x * 32, k0 = blockIdx.y * 32;
    int tx = threadIdx.x & 31, ty = threadIdx.x >> 5;
#pragma unroll
    for (int i = 0; i < 4; i++) {
        int k = ty + i * 8;
        tile[k][tx] = f2bf(W[(size_t)(k0 + k) * 3072 + n0 + tx]);
    }
    __syncthreads();
#pragma unroll
    for (int i = 0; i < 4; i++) {
        int n = ty + i * 8;
        Wt[(size_t)(n0 + n) * 1024 + k0 + tx] = tile[tx][n];
    }
}

// ---------- QKV GEMM: global_load_lds staging (m97 pattern), pre-swizzled source ----------
__global__ __launch_bounds__(256) void qkv_gemm(const u16* __restrict__ A, const u16* __restrict__ Bt,
                                                u16* __restrict__ C) {
    __shared__ alignas(16) u16 As[128 * 64];
    __shared__ alignas(16) u16 Bs[128 * 64];
    const int tid = threadIdx.x, l = tid & 63, w = tid >> 6;
    const int bm = blockIdx.y, bn = blockIdx.x;
    const int wm = w >> 1, wn = w & 1;
    const int c0 = l & 15, g = l >> 4;
    f32x4 acc[4][4] = {};
    for (int kt = 0; kt < 1024; kt += 64) {
        __syncthreads();
#pragma unroll
        for (int n = 0; n < 4; n++) {
            int i = tid + n * 256;
            int r = i >> 3, c = i & 7;
            int cs = c ^ (r & 7);
            u16* dstA = As + (size_t)(w * 64 + n * 256) * 8;   // wave-uniform
            u16* dstB = Bs + (size_t)(w * 64 + n * 256) * 8;
            gload16(A + (size_t)(bm * 128 + r) * 1024 + kt + cs * 8, dstA);
            gload16(Bt + (size_t)(bn * 128 + r) * 1024 + kt + cs * 8, dstB);
        }
        __syncthreads();
#pragma unroll
        for (int kk = 0; kk < 2; kk++) {
            bf16x8 af[4], bfr[4];
#pragma unroll
            for (int m = 0; m < 4; m++) {
                int row = wm * 64 + m * 16 + c0;
                af[m] = *(const bf16x8*)((const char*)As + row * 128 + (((g + kk * 4) ^ (row & 7)) << 4));
            }
#pragma unroll
            for (int n = 0; n < 4; n++) {
                int row = wn * 64 + n * 16 + c0;
                bfr[n] = *(const bf16x8*)((const char*)Bs + row * 128 + (((g + kk * 4) ^ (row & 7)) << 4));
            }
#pragma unroll
            for (int m = 0; m < 4; m++)
#pragma unroll
                for (int n = 0; n < 4; n++)
                    acc[m][n] = __builtin_amdgcn_mfma_f32_16x16x32_bf16(af[m], bfr[n], acc[m][n], 0, 0, 0);
        }
    }
#pragma unroll
    for (int m = 0; m < 4; m++)
#pragma unroll
        for (int n = 0; n < 4; n++)
#pragma unroll
            for (int j = 0; j < 4; j++) {
                int row = bm * 128 + wm * 64 + m * 16 + 4 * g + j;
                int col = bn * 128 + wn * 64 + n * 16 + c0;
                C[(size_t)row * 3072 + col] = f2bf(acc[m][n][j]);
            }
}

// ---------- V -> permuted V^T: Vtp[bh][d][spos], spos = (s&~63) | perm(s&63) ----------
__global__ __launch_bounds__(256) void transpose_v(const u16* __restrict__ QKV, u16* __restrict__ Vtp) {
    __shared__ u16 tile[64][72];
    const int bh = blockIdx.x >> 5, st = blockIdx.x & 31;
    const int b = bh >> 4, h = bh & 15;
    const u16* src = QKV + (size_t)b * S_LEN * 3072 + 2048 + h * 64;
    const int sl = threadIdx.x >> 2;
    const int cg = (threadIdx.x & 3) * 16;
#pragma unroll
    for (int ii = 0; ii < 2; ii++) {
        u16x8 v = *(const u16x8*)(src + (size_t)(st * 64 + sl) * 3072 + cg + ii * 8);
        *(u16x8*)&tile[sl][cg + ii * 8] = v;
    }
    __syncthreads();
    const int dl = threadIdx.x >> 2;
#pragma unroll
    for (int ii = 0; ii < 2; ii++) {
        u16x8 o;
#pragma unroll
        for (int q = 0; q < 8; q++) {
            int p = cg + ii * 8 + q;
            int kb = 2 * (p >> 5) + ((p >> 2) & 1);
            int t = kb * 16 + ((p >> 3) & 3) * 4 + (p & 3);
            o[q] = tile[t][dl];
        }
        *(u16x8*)(Vtp + ((size_t)bh * 64 + dl) * S_LEN + st * 64 + cg + ii * 8) = o;
    }
}

// ---------- Flash attention v5: 2 waves/block, 32 q-rows/wave (2 q-sets share each
// K/V frag read), l via ones-MFMA, precomputed LDS offsets, dbuf + 1 barrier/tile ----------
__global__ __launch_bounds__(128, 2) void attn5(const u16* __restrict__ QKV, const u16* __restrict__ Vtp,
                                                float* __restrict__ out) {
    __shared__ alignas(16) u16 Ks[2][64 * 64];   // [key][d] chunks, chunk^=(key&7); 8192B/buf
    __shared__ alignas(16) u16 Vs[2][64 * 64];   // [d][keypos] chunks, chunk^=(d&7)
    const int bid = blockIdx.x;
    const int wg = ((bid & 7) << 7) | (bid >> 3);   // XCD-chunked swizzle (bijective: 1024=8*128)
    const int tid = threadIdx.x, l = tid & 63, w = tid >> 6;   // w in {0,1}
    const int qt = wg & 31, bh = wg >> 5;
    const int b = bh >> 4, h = bh & 15;
    const int c0 = l & 15, g = l >> 4;
    const u16* Qb = QKV + (size_t)b * S_LEN * 3072 + h * 64;
    const u16* Kb = Qb + 1024;
    const u16* Vb = Vtp + (size_t)bh * 64 * S_LEN;

    // staging geometry: 512 chunks of 16B per operand tile, 4 per thread (128 thr)
    int rr[4], cc[4];
#pragma unroll
    for (int n = 0; n < 4; n++) {
        int i = tid + n * 128;
        rr[n] = i >> 3;
        cc[n] = ((i & 7) ^ (rr[n] & 7)) * 8;
    }

    // precomputed LDS read byte-offsets (loop-invariant)
    int koff[8], voff[8];
#pragma unroll
    for (int kb = 0; kb < 4; kb++)
#pragma unroll
        for (int kk = 0; kk < 2; kk++) {
            int key = kb * 16 + c0;
            koff[kb * 2 + kk] = key * 128 + (((g + kk * 4) ^ (key & 7)) << 4);
        }
#pragma unroll
    for (int kk = 0; kk < 2; kk++)
#pragma unroll
        for (int n = 0; n < 4; n++) {
            int d = n * 16 + c0;
            voff[kk * 4 + n] = d * 128 + (((g + 4 * kk) ^ (d & 7)) << 4);
        }

    // Q B-frags for 2 q-sets; fold (1/8)*log2(e)
    bf16x8 qf[2][2];
    {
        const float qs = 0.125f * 1.44269504f;
#pragma unroll
        for (int s = 0; s < 2; s++) {
            int qrow = qt * 64 + w * 32 + s * 16 + c0;
#pragma unroll
            for (int kk = 0; kk < 2; kk++) {
                u16x8 v = *(const u16x8*)(Qb + (size_t)qrow * 3072 + kk * 32 + g * 8);
                bf16x8 q;
#pragma unroll
                for (int j = 0; j < 8; j++) q[j] = (__bf16)(bf2f(v[j]) * qs);
                qf[s][kk] = q;
            }
        }
    }
    bf16x8 vone;
#pragma unroll
    for (int j = 0; j < 8; j++) vone[j] = (__bf16)1.0f;

    float m_r[2] = {-INFINITY, -INFINITY};
    f32x4 accO[2][4] = {};
    f32x4 accL[2] = {};

    // prologue: stage tile 0 into buf 0
#pragma unroll
    for (int n = 0; n < 4; n++) {
        gload16(Kb + (size_t)rr[n] * 3072 + cc[n], Ks[0] + (size_t)(w * 64 + n * 128) * 8);
        gload16(Vb + (size_t)rr[n] * S_LEN + cc[n], Vs[0] + (size_t)(w * 64 + n * 128) * 8);
    }

    for (int t = 0; t < 32; t++) {
        const int cur = t & 1;
        __syncthreads();  // buf[cur] staged (vmcnt drained at barrier) + prev reads done
        if (t + 1 < 32) {
            const int kvn = (t + 1) * 64;
#pragma unroll
            for (int n = 0; n < 4; n++) {
                gload16(Kb + (size_t)(kvn + rr[n]) * 3072 + cc[n], Ks[cur ^ 1] + (size_t)(w * 64 + n * 128) * 8);
                gload16(Vb + (size_t)rr[n] * S_LEN + kvn + cc[n], Vs[cur ^ 1] + (size_t)(w * 64 + n * 128) * 8);
            }
        }
        const char* Kc = (const char*)Ks[cur];
        const char* Vc = (const char*)Vs[cur];
        // QK^T (swapped): each kf read feeds both q-sets
        f32x4 sc[2][4] = {};
        __builtin_amdgcn_s_setprio(1);
#pragma unroll
        for (int kb = 0; kb < 4; kb++)
#pragma unroll
            for (int kk = 0; kk < 2; kk++) {
                bf16x8 kf = *(const bf16x8*)(Kc + koff[kb * 2 + kk]);
                sc[0][kb] = __builtin_amdgcn_mfma_f32_16x16x32_bf16(kf, qf[0][kk], sc[0][kb], 0, 0, 0);
                sc[1][kb] = __builtin_amdgcn_mfma_f32_16x16x32_bf16(kf, qf[1][kk], sc[1][kb], 0, 0, 0);
            }
        __builtin_amdgcn_s_setprio(0);
        // V fragment reads (latency hides under softmax)
        bf16x8 vf[2][4];
#pragma unroll
        for (int kk = 0; kk < 2; kk++)
#pragma unroll
            for (int n = 0; n < 4; n++)
                vf[kk][n] = *(const bf16x8*)(Vc + voff[kk * 4 + n]);
#pragma unroll
        for (int s = 0; s < 2; s++) {
            // tile max (max3-friendly triplets), reduce across the 4 g-groups
            float m0 = fmaxf(fmaxf(sc[s][0][0], sc[s][0][1]), sc[s][0][2]);
            float m1 = fmaxf(fmaxf(sc[s][0][3], sc[s][1][0]), sc[s][1][1]);
            float m2 = fmaxf(fmaxf(sc[s][1][2], sc[s][1][3]), sc[s][2][0]);
            float m3 = fmaxf(fmaxf(sc[s][2][1], sc[s][2][2]), sc[s][2][3]);
            float m4 = fmaxf(fmaxf(sc[s][3][0], sc[s][3][1]), sc[s][3][2]);
            float mx = fmaxf(fmaxf(fmaxf(m0, m1), m2), fmaxf(fmaxf(m3, m4), sc[s][3][3]));
            mx = fmaxf(mx, __shfl_xor(mx, 16));
            mx = fmaxf(mx, __shfl_xor(mx, 32));
            // defer-max (T13): rescale only when running max grows by > 8 (log2 domain)
            if (!__all(mx <= m_r[s] + 8.f)) {
                float mnew = fmaxf(m_r[s], mx);
                float alpha = __builtin_amdgcn_exp2f(m_r[s] - mnew);
                m_r[s] = mnew;
#pragma unroll
                for (int j = 0; j < 4; j++) {
                    float aj = __shfl(alpha, 20 * g + j);
                    accL[s][j] *= aj;
#pragma unroll
                    for (int n = 0; n < 4; n++) accO[s][n][j] *= aj;
                }
            }
#pragma unroll
            for (int kb = 0; kb < 4; kb++)
#pragma unroll
                for (int j = 0; j < 4; j++)
                    sc[s][kb][j] = __builtin_amdgcn_exp2f(sc[s][kb][j] - m_r[s]);
            // PV + l-accum: pf lane-local; accL = P @ ones (row-sum in accO's layout)
            __builtin_amdgcn_s_setprio(1);
#pragma unroll
            for (int kk = 0; kk < 2; kk++) {
                bf16x8 pf;
#pragma unroll
                for (int j = 0; j < 4; j++) {
                    pf[j]     = (__bf16)sc[s][2 * kk][j];
                    pf[j + 4] = (__bf16)sc[s][2 * kk + 1][j];
                }
                accL[s] = __builtin_amdgcn_mfma_f32_16x16x32_bf16(pf, vone, accL[s], 0, 0, 0);
#pragma unroll
                for (int n = 0; n < 4; n++)
                    accO[s][n] = __builtin_amdgcn_mfma_f32_16x16x32_bf16(pf, vf[kk][n], accO[s][n], 0, 0, 0);
            }
            __builtin_amdgcn_s_setprio(0);
        }
    }
    // epilogue: accL rows match accO rows (row j = q-offset 4g+j within the set)
#pragma unroll
    for (int s = 0; s < 2; s++)
#pragma unroll
        for (int j = 0; j < 4; j++) {
            float inv = 1.0f / accL[s][j];
            int row = qt * 64 + w * 32 + s * 16 + 4 * g + j;
#pragma unroll
            for (int n = 0; n < 4; n++)
                out[((size_t)b * S_LEN + row) * DMODEL + h * 64 + n * 16 + c0] = accO[s][n][j] * inv;
        }
}

extern "C" void kernel_launch(void* const* d_in, const int* in_sizes, int n_in,
                              void* d_out, int out_size, void* d_ws, size_t ws_size,
                              hipStream_t stream) {
    const float* X = (const float*)d_in[0];
    const float* W = (const float*)d_in[1];
    float* out = (float*)d_out;

    u16* Xb  = (u16*)d_ws;                        // 4096*1024 bf16
    u16* Wt  = Xb + (size_t)4096 * 1024;          // 3072*1024 bf16
    u16* QKV = Wt + (size_t)3072 * 1024;          // 4096*3072 bf16
    u16* Vtp = QKV + (size_t)4096 * 3072;         // 32*64*2048 bf16 (~48MB total)

    cvt_x<<<4096, 256, 0, stream>>>(X, Xb);
    transpose_w<<<dim3(96, 32), 256, 0, stream>>>(W, Wt);
    qkv_gemm<<<dim3(24, 32), 256, 0, stream>>>(Xb, Wt, QKV);
    transpose_v<<<1024, 256, 0, stream>>>(QKV, Vtp);
    attn5<<<1024, 128, 0, stream>>>(QKV, Vtp, out);
}